// Round 4
// baseline (714.534 us; speedup 1.0000x reference)
//
#include <hip/hip_runtime.h>

// NNGLS: y_decor, o_decor, o for N=200000, M=20, MLP 64->256->1.
//
// K1 (mlp_mfma_kernel): split-bf16 MFMA GEMM — byte-identical to R2/R3 so the
//     R4 profile attributes its counters cleanly (it has never appeared in
//     top-5; ~115 us by subtraction, unexplained => needs evidence).
// K2 (solve_kernel): R3's pair-split bordered solve, relaunched at
//     __launch_bounds__(64,1) / 64-thread blocks. R3's failure was the
//     (256,2) register budget (256 regs): SROA sent a[121] to scratch
//     (WRITE_SIZE 1.84 GB, VALUBusy 5%). With the (64,1) 512-reg unified
//     budget (R2 proved this regime: WRITE 1.5 MB, no scratch), the ~200
//     live floats/lane stay register-resident.

#define MM   20
#define PP   64
#define HH   256
#define EPSF 1e-12f

// jagged-uniform packing: lane stores rows r=2j+p, slot range c=2j..20
#define OFFJ(j) (21*(j) - (j)*((j)-1))
#define AIDX(j, c) (OFFJ(j) + (c) - 2*(j))

typedef __attribute__((ext_vector_type(8))) short bf16x8;
typedef __attribute__((ext_vector_type(4))) float f32x4;

static __device__ __forceinline__ unsigned short f2bf(float f) {
    unsigned int u = __builtin_bit_cast(unsigned int, f);
    u += 0x7fffu + ((u >> 16) & 1u);          // RNE
    return (unsigned short)(u >> 16);
}
static __device__ __forceinline__ float bf2f(unsigned short h) {
    unsigned int u = ((unsigned int)h) << 16;
    return __builtin_bit_cast(float, u);
}

__global__ __launch_bounds__(256, 2)
void mlp_mfma_kernel(const float* __restrict__ x,
                     const float* __restrict__ w1,
                     const float* __restrict__ b1,
                     const float* __restrict__ w2,
                     const float* __restrict__ b2,
                     float* __restrict__ o_out, int n)
{
    __shared__ __align__(16) short swh[PP * HH];   // 32 KB  w1 hi, frag order
    __shared__ __align__(16) short swl[PP * HH];   // 32 KB  w1 lo
    const int tid = threadIdx.x;

    {
        const int col = tid;
        const int t = col >> 4, nn = col & 15;
        #pragma unroll
        for (int g = 0; g < 8; ++g) {
            const int s = g >> 2, q = g & 3;
            bf16x8 hv, lv;
            #pragma unroll
            for (int u = 0; u < 8; ++u) {
                float v = w1[(g * 8 + u) * HH + col];
                unsigned short h = f2bf(v);
                hv[u] = (short)h;
                lv[u] = (short)f2bf(v - bf2f(h));
            }
            const int base = ((((t * 2 + s) * 4 + q) * 16) + nn) * 8;
            *(bf16x8*)&swh[base] = hv;
            *(bf16x8*)&swl[base] = lv;
        }
    }
    __syncthreads();

    const int lane = tid & 63;
    const int wv   = tid >> 6;
    const int nn   = lane & 15;
    const int q    = lane >> 4;
    const int wb   = blockIdx.x * 256 + wv * 64;

    float w2v[16], b1v[16];
    #pragma unroll
    for (int t = 0; t < 16; ++t) {
        w2v[t] = w2[t * 16 + nn];
        b1v[t] = b1[t * 16 + nn];
    }

    bf16x8 ah[4][2], al[4][2];
    #pragma unroll
    for (int mt = 0; mt < 4; ++mt) {
        const int row = wb + mt * 16 + nn;
        #pragma unroll
        for (int s = 0; s < 2; ++s) {
            float v[8];
            if (row < n) {
                const float* xp = x + (size_t)row * PP + s * 32 + q * 8;
                float4 va = *(const float4*)(xp);
                float4 vb = *(const float4*)(xp + 4);
                v[0]=va.x; v[1]=va.y; v[2]=va.z; v[3]=va.w;
                v[4]=vb.x; v[5]=vb.y; v[6]=vb.z; v[7]=vb.w;
            } else {
                #pragma unroll
                for (int u = 0; u < 8; ++u) v[u] = 0.0f;
            }
            bf16x8 h, l;
            #pragma unroll
            for (int u = 0; u < 8; ++u) {
                unsigned short hb = f2bf(v[u]);
                h[u] = (short)hb;
                l[u] = (short)f2bf(v[u] - bf2f(hb));
            }
            ah[mt][s] = h;
            al[mt][s] = l;
        }
    }

    float part[4][4];
    #pragma unroll
    for (int mt = 0; mt < 4; ++mt)
        #pragma unroll
        for (int r = 0; r < 4; ++r) part[mt][r] = 0.0f;

    for (int t = 0; t < 16; ++t) {
        f32x4 acc[4];
        #pragma unroll
        for (int mt = 0; mt < 4; ++mt) acc[mt] = (f32x4)(0.0f);
        #pragma unroll
        for (int s = 0; s < 2; ++s) {
            const int fb = ((((t * 2 + s) * 4 + q) * 16) + nn) * 8;
            bf16x8 bh = *(const bf16x8*)&swh[fb];
            bf16x8 bl = *(const bf16x8*)&swl[fb];
            #pragma unroll
            for (int mt = 0; mt < 4; ++mt) {
                acc[mt] = __builtin_amdgcn_mfma_f32_16x16x32_bf16(ah[mt][s], bh, acc[mt], 0, 0, 0);
                acc[mt] = __builtin_amdgcn_mfma_f32_16x16x32_bf16(al[mt][s], bh, acc[mt], 0, 0, 0);
                acc[mt] = __builtin_amdgcn_mfma_f32_16x16x32_bf16(ah[mt][s], bl, acc[mt], 0, 0, 0);
            }
        }
        #pragma unroll
        for (int mt = 0; mt < 4; ++mt)
            #pragma unroll
            for (int r = 0; r < 4; ++r)
                part[mt][r] = fmaf(fmaxf(acc[mt][r] + b1v[t], 0.0f), w2v[t], part[mt][r]);
    }

    #pragma unroll
    for (int w = 1; w < 16; w <<= 1)
        #pragma unroll
        for (int mt = 0; mt < 4; ++mt)
            #pragma unroll
            for (int r = 0; r < 4; ++r)
                part[mt][r] += __shfl_xor(part[mt][r], w, 64);

    const float bb = b2[0];
    if (nn == 0) {
        #pragma unroll
        for (int mt = 0; mt < 4; ++mt) {
            const int row = wb + mt * 16 + q * 4;
            if (row < n) {
                float4 o4 = make_float4(part[mt][0] + bb, part[mt][1] + bb,
                                        part[mt][2] + bb, part[mt][3] + bb);
                *(float4*)&o_out[row] = o4;
            }
        }
    }
}

__global__ __launch_bounds__(64, 1)
void solve_kernel(const float* __restrict__ pos,
                  const float* __restrict__ y,
                  const int*   __restrict__ nbr,
                  const float* __restrict__ theta,
                  const float* __restrict__ o_in,
                  float* __restrict__ yd,
                  float* __restrict__ od, int n)
{
    const int tid = threadIdx.x;
    const int p   = tid & 1;                              // parity within pair
    const int i   = (blockIdx.x * 64 + tid) >> 1;         // node id (pair-shared)
    if (i >= n) return;                                   // uniform (grid exact)

    const float sigma_sq = theta[0];
    const float phi      = theta[1];
    const float tau      = theta[2];
    const float tau_sq   = tau * sigma_sq;

    const float L2E = 1.44269504088896340736f;
    const float c1  = -phi * L2E;                         // exp(-phi*d)=exp2(c1*d)
    const float c0  = __builtin_amdgcn_logf(sigma_sq);    // log2(sigma^2)

    // ---- gather neighbor indices ----
    int idx[MM];
    const int4* nb4 = (const int4*)(nbr + (size_t)i * MM);
    #pragma unroll
    for (int k = 0; k < MM / 4; ++k) {
        int4 v = nb4[k];
        idx[4*k] = v.x; idx[4*k+1] = v.y; idx[4*k+2] = v.z; idx[4*k+3] = v.w;
    }

    // ---- rhs gathers first (frees idx before the build's register peak) ----
    float ry_[11], ro_[11];
    #pragma unroll
    for (int j = 0; j < 10; ++j) {
        const int ii = p ? idx[2*j+1] : idx[2*j];
        ry_[j] = y[ii];
        ro_[j] = o_in[ii];
    }
    {
        const float ys = y[i], os = o_in[i];
        ry_[10] = p ? 0.0f : ys;
        ro_[10] = p ? 0.0f : os;
    }

    // ---- gather positions: neighbors 0..19, self at 20 ----
    float px[21], py[21];
    const float2* pos2 = (const float2*)pos;
    #pragma unroll
    for (int j = 0; j < MM; ++j) {
        float2 pp = pos2[idx[j]];
        px[j] = pp.x; py[j] = pp.y;
    }
    {
        float2 pp = pos2[i];
        px[20] = pp.x; py[20] = pp.y;
    }

    const float sqrtEPS = __builtin_amdgcn_sqrtf(EPSF);
    const float diagA   = __builtin_amdgcn_exp2f(fmaf(sqrtEPS, c1, c0)) + tau_sq;

    // ---- build my jagged rows of the bordered 21x21 ----
    float a[121];
    #pragma unroll
    for (int j = 0; j < 10; ++j) {
        const float rx = p ? px[2*j+1] : px[2*j];
        const float ry = p ? py[2*j+1] : py[2*j];
        a[AIDX(j, 2*j)] = diagA;                    // p==1 slot is padding
        {
            float dx = px[2*j] - px[2*j+1];
            float dy = py[2*j] - py[2*j+1];
            float d  = __builtin_amdgcn_sqrtf(fmaf(dx, dx, fmaf(dy, dy, EPSF)));
            float ov = __builtin_amdgcn_exp2f(fmaf(d, c1, c0));
            a[AIDX(j, 2*j+1)] = p ? diagA : ov;
        }
        #pragma unroll
        for (int c = 2*j + 2; c <= 20; ++c) {
            float dx = rx - px[c];
            float dy = ry - py[c];
            float d  = __builtin_amdgcn_sqrtf(fmaf(dx, dx, fmaf(dy, dy, EPSF)));
            a[AIDX(j, c)] = __builtin_amdgcn_exp2f(fmaf(d, c1, c0));
        }
    }
    a[AIDX(10, 20)] = sigma_sq + tau;               // row 20 diag (phantom row 21 ok)

    // ---- 20 symmetric elimination steps, fully unrolled ----
    float pr[22];
    pr[21] = 0.0f;                       // phantom row's multiplier source -> no-op
    #pragma unroll
    for (int k = 0; k < 20; ++k) {
        const int jk = k >> 1;
        const int kp = k & 1;
        #pragma unroll
        for (int c = k; c <= 20; ++c) {
            float mine  = a[AIDX(jk, c)];
            float other = __shfl_xor(mine, 1, 64);   // pair-local swizzle
            pr[c] = (p == kp) ? mine : other;
        }
        float pyv, pov;
        {
            float my_y = ry_[jk], my_o = ro_[jk];
            float ot_y = __shfl_xor(my_y, 1, 64);
            float ot_o = __shfl_xor(my_o, 1, 64);
            pyv = (p == kp) ? my_y : ot_y;
            pov = (p == kp) ? my_o : ot_o;
        }
        const float pd = pr[k];
        float rp = __builtin_amdgcn_rcpf(pd);
        rp = rp * (2.0f - pd * rp);                  // Newton refine
        #pragma unroll
        for (int j = 0; j <= 10; ++j) {
            if (2*j < k) continue;                   // compile-time prune
            float m;
            if (2*j == k) m = p ? pr[2*j+1] * rp : 0.0f;      // lane0 row IS pivot
            else          m = (p ? pr[2*j+1] : pr[2*j]) * rp; // j==10,p==1: pr[21]=0
            #pragma unroll
            for (int c = 2*j; c <= 20; ++c)
                a[AIDX(j, c)] = fmaf(-m, pr[c], a[AIDX(j, c)]);
            ry_[j] = fmaf(-m, pyv, ry_[j]);
            ro_[j] = fmaf(-m, pov, ro_[j]);
        }
    }

    const float f = a[AIDX(10, 20)];     // lane0: Schur complement == f_i
    float is = __builtin_amdgcn_rsqf(f);
    is = is * fmaf(-0.5f * f * is, is, 1.5f);
    if (p == 0) {
        yd[i] = ry_[10] * is;
        od[i] = ro_[10] * is;
    }
}

extern "C" void kernel_launch(void* const* d_in, const int* in_sizes, int n_in,
                              void* d_out, int out_size, void* d_ws, size_t ws_size,
                              hipStream_t stream)
{
    const float* x     = (const float*)d_in[0];
    const float* pos   = (const float*)d_in[1];
    const float* y     = (const float*)d_in[2];
    const int*   nbr   = (const int*)  d_in[3];
    const float* theta = (const float*)d_in[4];
    const float* w1    = (const float*)d_in[5];
    const float* b1    = (const float*)d_in[6];
    const float* w2    = (const float*)d_in[7];
    const float* b2    = (const float*)d_in[8];

    const int n = in_sizes[2];                 // N
    float* out = (float*)d_out;
    float* yd = out;
    float* od = out + (size_t)n;
    float* oo = out + 2 * (size_t)n;

    mlp_mfma_kernel<<<(n + 255) / 256, 256, 0, stream>>>(x, w1, b1, w2, b2, oo, n);
    // 2 lanes per node -> 2n threads; 64-thread blocks, (64,1) = 512-reg budget
    solve_kernel<<<(2 * n + 63) / 64, 64, 0, stream>>>(pos, y, nbr, theta, oo, yd, od, n);
}

// Round 5
// 256.912 us; speedup vs baseline: 2.7812x; 2.7812x over previous
//
#include <hip/hip_runtime.h>

// NNGLS: y_decor, o_decor, o for N=200000, M=20, MLP 64->256->1.
//
// K1 (mlp_mfma_kernel): split-bf16 MFMA GEMM. R5 change: the 16-iter t-loop
//     is now #pragma unroll'd. Previously t was a RUNTIME index into b1v[t]
//     / w2v[t] per-thread arrays -> alloca -> scratch load inside the
//     accumulation chain every iteration (R1's fp32 MLP showed the same
//     disease directly: WRITE_SIZE 17.2 MB vs 0.8 MB of real output).
// K2 (solve_kernel): R2-exact per-thread bordered solve (known: 118 us,
//     WRITE_SIZE == outputs, zero scratch). Pair-split abandoned: R3/R4
//     proved its alloca never reaches registers (SROA bail -> LDS+scratch).
//     R5 launches solve as TWO half-N dispatches (~59 us each) purely so the
//     slower of {solve-half, mlp} owns the top-5 counters next round.

#define MM   20
#define PP   64
#define HH   256
#define EPSF 1e-12f
#define UT(r, c) ((r)*21 - ((r)*((r)-1))/2 + ((c)-(r)))

typedef __attribute__((ext_vector_type(8))) short bf16x8;
typedef __attribute__((ext_vector_type(4))) float f32x4;

static __device__ __forceinline__ unsigned short f2bf(float f) {
    unsigned int u = __builtin_bit_cast(unsigned int, f);
    u += 0x7fffu + ((u >> 16) & 1u);          // RNE
    return (unsigned short)(u >> 16);
}
static __device__ __forceinline__ float bf2f(unsigned short h) {
    unsigned int u = ((unsigned int)h) << 16;
    return __builtin_bit_cast(float, u);
}

__global__ __launch_bounds__(256, 2)
void mlp_mfma_kernel(const float* __restrict__ x,
                     const float* __restrict__ w1,
                     const float* __restrict__ b1,
                     const float* __restrict__ w2,
                     const float* __restrict__ b2,
                     float* __restrict__ o_out, int n)
{
    __shared__ __align__(16) short swh[PP * HH];   // 32 KB  w1 hi, frag order
    __shared__ __align__(16) short swl[PP * HH];   // 32 KB  w1 lo
    const int tid = threadIdx.x;

    {
        const int col = tid;
        const int t = col >> 4, nn = col & 15;
        #pragma unroll
        for (int g = 0; g < 8; ++g) {
            const int s = g >> 2, q = g & 3;
            bf16x8 hv, lv;
            #pragma unroll
            for (int u = 0; u < 8; ++u) {
                float v = w1[(g * 8 + u) * HH + col];
                unsigned short h = f2bf(v);
                hv[u] = (short)h;
                lv[u] = (short)f2bf(v - bf2f(h));
            }
            const int base = ((((t * 2 + s) * 4 + q) * 16) + nn) * 8;
            *(bf16x8*)&swh[base] = hv;
            *(bf16x8*)&swl[base] = lv;
        }
    }
    __syncthreads();

    const int lane = tid & 63;
    const int wv   = tid >> 6;
    const int nn   = lane & 15;
    const int q    = lane >> 4;
    const int wb   = blockIdx.x * 256 + wv * 64;

    float w2v[16], b1v[16];
    #pragma unroll
    for (int t = 0; t < 16; ++t) {
        w2v[t] = w2[t * 16 + nn];
        b1v[t] = b1[t * 16 + nn];
    }

    bf16x8 ah[4][2], al[4][2];
    #pragma unroll
    for (int mt = 0; mt < 4; ++mt) {
        const int row = wb + mt * 16 + nn;
        #pragma unroll
        for (int s = 0; s < 2; ++s) {
            float v[8];
            if (row < n) {
                const float* xp = x + (size_t)row * PP + s * 32 + q * 8;
                float4 va = *(const float4*)(xp);
                float4 vb = *(const float4*)(xp + 4);
                v[0]=va.x; v[1]=va.y; v[2]=va.z; v[3]=va.w;
                v[4]=vb.x; v[5]=vb.y; v[6]=vb.z; v[7]=vb.w;
            } else {
                #pragma unroll
                for (int u = 0; u < 8; ++u) v[u] = 0.0f;
            }
            bf16x8 h, l;
            #pragma unroll
            for (int u = 0; u < 8; ++u) {
                unsigned short hb = f2bf(v[u]);
                h[u] = (short)hb;
                l[u] = (short)f2bf(v[u] - bf2f(hb));
            }
            ah[mt][s] = h;
            al[mt][s] = l;
        }
    }

    float part[4][4];
    #pragma unroll
    for (int mt = 0; mt < 4; ++mt)
        #pragma unroll
        for (int r = 0; r < 4; ++r) part[mt][r] = 0.0f;

    #pragma unroll            // R5: compile-time t => b1v[t]/w2v[t] stay SSA (no alloca)
    for (int t = 0; t < 16; ++t) {
        f32x4 acc[4];
        #pragma unroll
        for (int mt = 0; mt < 4; ++mt) acc[mt] = (f32x4)(0.0f);
        #pragma unroll
        for (int s = 0; s < 2; ++s) {
            const int fb = ((((t * 2 + s) * 4 + q) * 16) + nn) * 8;
            bf16x8 bh = *(const bf16x8*)&swh[fb];
            bf16x8 bl = *(const bf16x8*)&swl[fb];
            #pragma unroll
            for (int mt = 0; mt < 4; ++mt) {
                acc[mt] = __builtin_amdgcn_mfma_f32_16x16x32_bf16(ah[mt][s], bh, acc[mt], 0, 0, 0);
                acc[mt] = __builtin_amdgcn_mfma_f32_16x16x32_bf16(al[mt][s], bh, acc[mt], 0, 0, 0);
                acc[mt] = __builtin_amdgcn_mfma_f32_16x16x32_bf16(ah[mt][s], bl, acc[mt], 0, 0, 0);
            }
        }
        #pragma unroll
        for (int mt = 0; mt < 4; ++mt)
            #pragma unroll
            for (int r = 0; r < 4; ++r)
                part[mt][r] = fmaf(fmaxf(acc[mt][r] + b1v[t], 0.0f), w2v[t], part[mt][r]);
    }

    #pragma unroll
    for (int w = 1; w < 16; w <<= 1)
        #pragma unroll
        for (int mt = 0; mt < 4; ++mt)
            #pragma unroll
            for (int r = 0; r < 4; ++r)
                part[mt][r] += __shfl_xor(part[mt][r], w, 64);

    const float bb = b2[0];
    if (nn == 0) {
        #pragma unroll
        for (int mt = 0; mt < 4; ++mt) {
            const int row = wb + mt * 16 + q * 4;
            if (row < n) {
                float4 o4 = make_float4(part[mt][0] + bb, part[mt][1] + bb,
                                        part[mt][2] + bb, part[mt][3] + bb);
                *(float4*)&o_out[row] = o4;
            }
        }
    }
}

__global__ __launch_bounds__(64, 1)
void solve_kernel(const float* __restrict__ pos,
                  const float* __restrict__ y,
                  const int*   __restrict__ nbr,
                  const float* __restrict__ theta,
                  const float* __restrict__ o_in,
                  float* __restrict__ yd,
                  float* __restrict__ od, int base, int n)
{
    const int i = base + blockIdx.x * 64 + threadIdx.x;
    if (i >= n) return;

    const float sigma_sq = theta[0];
    const float phi      = theta[1];
    const float tau      = theta[2];
    const float tau_sq   = tau * sigma_sq;

    const float L2E = 1.44269504088896340736f;
    const float c1  = -phi * L2E;                       // exp(-phi*d) = exp2(c1*d)
    const float c0  = __builtin_amdgcn_logf(sigma_sq);  // log2(sigma^2)

    int idx[MM];
    const int4* nb4 = (const int4*)(nbr + (size_t)i * MM);
    #pragma unroll
    for (int k = 0; k < MM / 4; ++k) {
        int4 v = nb4[k];
        idx[4*k] = v.x; idx[4*k+1] = v.y; idx[4*k+2] = v.z; idx[4*k+3] = v.w;
    }

    float px[21], py[21];
    const float2* pos2 = (const float2*)pos;
    #pragma unroll
    for (int j = 0; j < MM; ++j) {
        float2 p = pos2[idx[j]];
        px[j] = p.x; py[j] = p.y;
    }
    {
        float2 p = pos2[i];
        px[20] = p.x; py[20] = p.y;
    }

    const float sqrtEPS = __builtin_amdgcn_sqrtf(EPSF);
    const float diagA   = __builtin_amdgcn_exp2f(fmaf(sqrtEPS, c1, c0)) + tau_sq;

    // build bordered 21x21 covariance (upper-packed), fully unrolled
    float a[231];
    #pragma unroll
    for (int r = 0; r < 21; ++r) {
        #pragma unroll
        for (int c = r; c < 21; ++c) {
            if (r == c) {
                a[UT(r, c)] = (r == 20) ? (sigma_sq + tau) : diagA;
            } else {
                float dx = px[r] - px[c];
                float dy = py[r] - py[c];
                float d2 = fmaf(dx, dx, fmaf(dy, dy, EPSF));
                float d  = __builtin_amdgcn_sqrtf(d2);
                a[UT(r, c)] = __builtin_amdgcn_exp2f(fmaf(d, c1, c0));
            }
        }
    }

    float yv[21], ov[21];
    #pragma unroll
    for (int j = 0; j < MM; ++j) {
        yv[j] = y[idx[j]];
        ov[j] = o_in[idx[j]];
    }
    yv[20] = y[i];
    ov[20] = o_in[i];

    // ---- 20 elimination steps, LOOPED (R2-exact; known scratch-free) ----
    float pr[21], pd, pyv, pov;
    #pragma unroll 1
    for (int k = 0; k < 20; ++k) {
        switch (k) {
#define CASE(K) case K: {                                     \
            pd = a[UT(K, K)]; pyv = yv[K]; pov = ov[K];       \
            _Pragma("unroll")                                 \
            for (int c = K; c < 21; ++c) pr[c] = a[UT(K, c)]; \
        } break;
        CASE(0)  CASE(1)  CASE(2)  CASE(3)  CASE(4)
        CASE(5)  CASE(6)  CASE(7)  CASE(8)  CASE(9)
        CASE(10) CASE(11) CASE(12) CASE(13) CASE(14)
        CASE(15) CASE(16) CASE(17) CASE(18) CASE(19)
#undef CASE
        default: break;
        }
        float rp = __builtin_amdgcn_rcpf(pd);
        rp = rp * (2.0f - pd * rp);                 // Newton refine
        float m[21];
        #pragma unroll
        for (int r = 0; r < 21; ++r) {
            float mr = pr[r] * rp;
            m[r] = (r > k) ? mr : 0.0f;             // rows <= k: exact no-op
        }
        #pragma unroll
        for (int r = 0; r < 21; ++r) {
            #pragma unroll
            for (int c = r; c < 21; ++c)
                a[UT(r, c)] = fmaf(-m[r], pr[c], a[UT(r, c)]);
            yv[r] = fmaf(-m[r], pyv, yv[r]);
            ov[r] = fmaf(-m[r], pov, ov[r]);
        }
    }

    const float f = a[UT(20, 20)];                  // Schur complement == f_i
    float is = __builtin_amdgcn_rsqf(f);
    is = is * fmaf(-0.5f * f * is, is, 1.5f);
    yd[i] = yv[20] * is;
    od[i] = ov[20] * is;
}

extern "C" void kernel_launch(void* const* d_in, const int* in_sizes, int n_in,
                              void* d_out, int out_size, void* d_ws, size_t ws_size,
                              hipStream_t stream)
{
    const float* x     = (const float*)d_in[0];
    const float* pos   = (const float*)d_in[1];
    const float* y     = (const float*)d_in[2];
    const int*   nbr   = (const int*)  d_in[3];
    const float* theta = (const float*)d_in[4];
    const float* w1    = (const float*)d_in[5];
    const float* b1    = (const float*)d_in[6];
    const float* w2    = (const float*)d_in[7];
    const float* b2    = (const float*)d_in[8];

    const int n = in_sizes[2];                 // N
    float* out = (float*)d_out;
    float* yd = out;
    float* od = out + (size_t)n;
    float* oo = out + 2 * (size_t)n;

    mlp_mfma_kernel<<<(n + 255) / 256, 256, 0, stream>>>(x, w1, b1, w2, b2, oo, n);

    // Two half-N solves (instrumentation: each ~half dur so the slower KERNEL
    // type owns next round's top-5 counters regardless of which it is).
    const int half = n / 2;
    solve_kernel<<<(half + 63) / 64, 64, 0, stream>>>(pos, y, nbr, theta, oo, yd, od, 0, half);
    solve_kernel<<<(n - half + 63) / 64, 64, 0, stream>>>(pos, y, nbr, theta, oo, yd, od, half, n);
}

// Round 6
// 241.387 us; speedup vs baseline: 2.9601x; 1.0643x over previous
//
#include <hip/hip_runtime.h>

// NNGLS: y_decor, o_decor, o for N=200000, M=20, MLP 64->256->1.
//
// K1 (mlp_mfma_kernel): split-bf16 MFMA GEMM. R6 change: __launch_bounds__
//     (256,1) instead of (256,2). The (256,2) bound imposed a 128-VGPR cap;
//     evidence: R1 mlp VGPR_Count==128 exactly + WRITE_SIZE 17.2 MB vs
//     0.8 MB real output (16.4 MB scratch). MFMA variant needs ~160+ regs
//     (ah/al 64 + acc 16 + part 16 + b1v/w2v 32 + temps) -> spilled in the
//     hot loop under the cap -> ~116 us. (256,1) lifts the cap to 256+.
// K2 (solve_kernel): R2-exact per-thread bordered solve, single full-N
//     dispatch (118 us known; R5's half-split cost 140 total -> reverted).
//     Known state: a[231] AGPR-resident, 1 wave/SIMD, latency-bound.
//     Restructuring it is the next experiment AFTER mlp counters are clean.

#define MM   20
#define PP   64
#define HH   256
#define EPSF 1e-12f
#define UT(r, c) ((r)*21 - ((r)*((r)-1))/2 + ((c)-(r)))

typedef __attribute__((ext_vector_type(8))) short bf16x8;
typedef __attribute__((ext_vector_type(4))) float f32x4;

static __device__ __forceinline__ unsigned short f2bf(float f) {
    unsigned int u = __builtin_bit_cast(unsigned int, f);
    u += 0x7fffu + ((u >> 16) & 1u);          // RNE
    return (unsigned short)(u >> 16);
}
static __device__ __forceinline__ float bf2f(unsigned short h) {
    unsigned int u = ((unsigned int)h) << 16;
    return __builtin_bit_cast(float, u);
}

__global__ __launch_bounds__(256, 1)   // R6: was (256,2) => 128-VGPR cap => spills
void mlp_mfma_kernel(const float* __restrict__ x,
                     const float* __restrict__ w1,
                     const float* __restrict__ b1,
                     const float* __restrict__ w2,
                     const float* __restrict__ b2,
                     float* __restrict__ o_out, int n)
{
    __shared__ __align__(16) short swh[PP * HH];   // 32 KB  w1 hi, frag order
    __shared__ __align__(16) short swl[PP * HH];   // 32 KB  w1 lo
    const int tid = threadIdx.x;

    {
        const int col = tid;
        const int t = col >> 4, nn = col & 15;
        #pragma unroll
        for (int g = 0; g < 8; ++g) {
            const int s = g >> 2, q = g & 3;
            bf16x8 hv, lv;
            #pragma unroll
            for (int u = 0; u < 8; ++u) {
                float v = w1[(g * 8 + u) * HH + col];
                unsigned short h = f2bf(v);
                hv[u] = (short)h;
                lv[u] = (short)f2bf(v - bf2f(h));
            }
            const int base = ((((t * 2 + s) * 4 + q) * 16) + nn) * 8;
            *(bf16x8*)&swh[base] = hv;
            *(bf16x8*)&swl[base] = lv;
        }
    }
    __syncthreads();

    const int lane = tid & 63;
    const int wv   = tid >> 6;
    const int nn   = lane & 15;
    const int q    = lane >> 4;
    const int wb   = blockIdx.x * 256 + wv * 64;

    float w2v[16], b1v[16];
    #pragma unroll
    for (int t = 0; t < 16; ++t) {
        w2v[t] = w2[t * 16 + nn];
        b1v[t] = b1[t * 16 + nn];
    }

    bf16x8 ah[4][2], al[4][2];
    #pragma unroll
    for (int mt = 0; mt < 4; ++mt) {
        const int row = wb + mt * 16 + nn;
        #pragma unroll
        for (int s = 0; s < 2; ++s) {
            float v[8];
            if (row < n) {
                const float* xp = x + (size_t)row * PP + s * 32 + q * 8;
                float4 va = *(const float4*)(xp);
                float4 vb = *(const float4*)(xp + 4);
                v[0]=va.x; v[1]=va.y; v[2]=va.z; v[3]=va.w;
                v[4]=vb.x; v[5]=vb.y; v[6]=vb.z; v[7]=vb.w;
            } else {
                #pragma unroll
                for (int u = 0; u < 8; ++u) v[u] = 0.0f;
            }
            bf16x8 h, l;
            #pragma unroll
            for (int u = 0; u < 8; ++u) {
                unsigned short hb = f2bf(v[u]);
                h[u] = (short)hb;
                l[u] = (short)f2bf(v[u] - bf2f(hb));
            }
            ah[mt][s] = h;
            al[mt][s] = l;
        }
    }

    float part[4][4];
    #pragma unroll
    for (int mt = 0; mt < 4; ++mt)
        #pragma unroll
        for (int r = 0; r < 4; ++r) part[mt][r] = 0.0f;

    #pragma unroll
    for (int t = 0; t < 16; ++t) {
        f32x4 acc[4];
        #pragma unroll
        for (int mt = 0; mt < 4; ++mt) acc[mt] = (f32x4)(0.0f);
        #pragma unroll
        for (int s = 0; s < 2; ++s) {
            const int fb = ((((t * 2 + s) * 4 + q) * 16) + nn) * 8;
            bf16x8 bh = *(const bf16x8*)&swh[fb];
            bf16x8 bl = *(const bf16x8*)&swl[fb];
            #pragma unroll
            for (int mt = 0; mt < 4; ++mt) {
                acc[mt] = __builtin_amdgcn_mfma_f32_16x16x32_bf16(ah[mt][s], bh, acc[mt], 0, 0, 0);
                acc[mt] = __builtin_amdgcn_mfma_f32_16x16x32_bf16(al[mt][s], bh, acc[mt], 0, 0, 0);
                acc[mt] = __builtin_amdgcn_mfma_f32_16x16x32_bf16(ah[mt][s], bl, acc[mt], 0, 0, 0);
            }
        }
        #pragma unroll
        for (int mt = 0; mt < 4; ++mt)
            #pragma unroll
            for (int r = 0; r < 4; ++r)
                part[mt][r] = fmaf(fmaxf(acc[mt][r] + b1v[t], 0.0f), w2v[t], part[mt][r]);
    }

    #pragma unroll
    for (int w = 1; w < 16; w <<= 1)
        #pragma unroll
        for (int mt = 0; mt < 4; ++mt)
            #pragma unroll
            for (int r = 0; r < 4; ++r)
                part[mt][r] += __shfl_xor(part[mt][r], w, 64);

    const float bb = b2[0];
    if (nn == 0) {
        #pragma unroll
        for (int mt = 0; mt < 4; ++mt) {
            const int row = wb + mt * 16 + q * 4;
            if (row < n) {
                float4 o4 = make_float4(part[mt][0] + bb, part[mt][1] + bb,
                                        part[mt][2] + bb, part[mt][3] + bb);
                *(float4*)&o_out[row] = o4;
            }
        }
    }
}

__global__ __launch_bounds__(64, 1)
void solve_kernel(const float* __restrict__ pos,
                  const float* __restrict__ y,
                  const int*   __restrict__ nbr,
                  const float* __restrict__ theta,
                  const float* __restrict__ o_in,
                  float* __restrict__ yd,
                  float* __restrict__ od, int n)
{
    const int i = blockIdx.x * 64 + threadIdx.x;
    if (i >= n) return;

    const float sigma_sq = theta[0];
    const float phi      = theta[1];
    const float tau      = theta[2];
    const float tau_sq   = tau * sigma_sq;

    const float L2E = 1.44269504088896340736f;
    const float c1  = -phi * L2E;                       // exp(-phi*d) = exp2(c1*d)
    const float c0  = __builtin_amdgcn_logf(sigma_sq);  // log2(sigma^2)

    int idx[MM];
    const int4* nb4 = (const int4*)(nbr + (size_t)i * MM);
    #pragma unroll
    for (int k = 0; k < MM / 4; ++k) {
        int4 v = nb4[k];
        idx[4*k] = v.x; idx[4*k+1] = v.y; idx[4*k+2] = v.z; idx[4*k+3] = v.w;
    }

    float px[21], py[21];
    const float2* pos2 = (const float2*)pos;
    #pragma unroll
    for (int j = 0; j < MM; ++j) {
        float2 p = pos2[idx[j]];
        px[j] = p.x; py[j] = p.y;
    }
    {
        float2 p = pos2[i];
        px[20] = p.x; py[20] = p.y;
    }

    const float sqrtEPS = __builtin_amdgcn_sqrtf(EPSF);
    const float diagA   = __builtin_amdgcn_exp2f(fmaf(sqrtEPS, c1, c0)) + tau_sq;

    // build bordered 21x21 covariance (upper-packed), fully unrolled
    float a[231];
    #pragma unroll
    for (int r = 0; r < 21; ++r) {
        #pragma unroll
        for (int c = r; c < 21; ++c) {
            if (r == c) {
                a[UT(r, c)] = (r == 20) ? (sigma_sq + tau) : diagA;
            } else {
                float dx = px[r] - px[c];
                float dy = py[r] - py[c];
                float d2 = fmaf(dx, dx, fmaf(dy, dy, EPSF));
                float d  = __builtin_amdgcn_sqrtf(d2);
                a[UT(r, c)] = __builtin_amdgcn_exp2f(fmaf(d, c1, c0));
            }
        }
    }

    float yv[21], ov[21];
    #pragma unroll
    for (int j = 0; j < MM; ++j) {
        yv[j] = y[idx[j]];
        ov[j] = o_in[idx[j]];
    }
    yv[20] = y[i];
    ov[20] = o_in[i];

    // ---- 20 elimination steps, LOOPED (R2-exact; known scratch-free) ----
    float pr[21], pd, pyv, pov;
    #pragma unroll 1
    for (int k = 0; k < 20; ++k) {
        switch (k) {
#define CASE(K) case K: {                                     \
            pd = a[UT(K, K)]; pyv = yv[K]; pov = ov[K];       \
            _Pragma("unroll")                                 \
            for (int c = K; c < 21; ++c) pr[c] = a[UT(K, c)]; \
        } break;
        CASE(0)  CASE(1)  CASE(2)  CASE(3)  CASE(4)
        CASE(5)  CASE(6)  CASE(7)  CASE(8)  CASE(9)
        CASE(10) CASE(11) CASE(12) CASE(13) CASE(14)
        CASE(15) CASE(16) CASE(17) CASE(18) CASE(19)
#undef CASE
        default: break;
        }
        float rp = __builtin_amdgcn_rcpf(pd);
        rp = rp * (2.0f - pd * rp);                 // Newton refine
        float m[21];
        #pragma unroll
        for (int r = 0; r < 21; ++r) {
            float mr = pr[r] * rp;
            m[r] = (r > k) ? mr : 0.0f;             // rows <= k: exact no-op
        }
        #pragma unroll
        for (int r = 0; r < 21; ++r) {
            #pragma unroll
            for (int c = r; c < 21; ++c)
                a[UT(r, c)] = fmaf(-m[r], pr[c], a[UT(r, c)]);
            yv[r] = fmaf(-m[r], pyv, yv[r]);
            ov[r] = fmaf(-m[r], pov, ov[r]);
        }
    }

    const float f = a[UT(20, 20)];                  // Schur complement == f_i
    float is = __builtin_amdgcn_rsqf(f);
    is = is * fmaf(-0.5f * f * is, is, 1.5f);
    yd[i] = yv[20] * is;
    od[i] = ov[20] * is;
}

extern "C" void kernel_launch(void* const* d_in, const int* in_sizes, int n_in,
                              void* d_out, int out_size, void* d_ws, size_t ws_size,
                              hipStream_t stream)
{
    const float* x     = (const float*)d_in[0];
    const float* pos   = (const float*)d_in[1];
    const float* y     = (const float*)d_in[2];
    const int*   nbr   = (const int*)  d_in[3];
    const float* theta = (const float*)d_in[4];
    const float* w1    = (const float*)d_in[5];
    const float* b1    = (const float*)d_in[6];
    const float* w2    = (const float*)d_in[7];
    const float* b2    = (const float*)d_in[8];

    const int n = in_sizes[2];                 // N
    float* out = (float*)d_out;
    float* yd = out;
    float* od = out + (size_t)n;
    float* oo = out + 2 * (size_t)n;

    mlp_mfma_kernel<<<(n + 255) / 256, 256, 0, stream>>>(x, w1, b1, w2, b2, oo, n);
    solve_kernel<<<(n + 63) / 64, 64, 0, stream>>>(pos, y, nbr, theta, oo, yd, od, n);
}